// Round 2
// baseline (13.229 us; speedup 1.0000x reference)
//
#include <hip/hip_runtime.h>

#define NLOG2E -1.4426950408889634f   // -log2(e)

// Reduce-scatter round: lanes exchange half their live values with lane^M,
// halving values-per-lane. After 5 rounds (M=1..16) each lane in a 32-group
// holds one fully-summed value at index bitrev5(lane&31).
template<int M, int HALF>
__device__ __forceinline__ void rs_round(float* v, int lane) {
  const bool up = (lane & M) != 0;
#pragma unroll
  for (int i = 0; i < HALF; ++i) {
    float send = up ? v[i] : v[i + HALF];
    float recv = __shfl_xor(send, M, 64);
    v[i] = (up ? v[i + HALF] : v[i]) + recv;
  }
}

// 2 waves per output row, each covering 256 of the 512 triples.
// Block = 256 threads = 4 waves = 2 rows. Partial sums joined via LDS.
__global__ __launch_bounds__(256, 6) void behler_g3_kernel(
    const float* __restrict__ r_ij, const float* __restrict__ r_ik,
    const float* __restrict__ r_jk, const int* __restrict__ mask,
    const float* __restrict__ etas, float* __restrict__ out)
{
  const int tid  = threadIdx.x;
  const int lane = tid & 63;
  const int wave = tid >> 6;
  const int half = wave & 1;            // which half of the row's triples
  const int row  = blockIdx.x * 2 + (wave >> 1);

  const size_t base = (size_t)row * 512 + (size_t)half * 256;
  // one float4 per stream per lane: 64 lanes x 4 = 256 triples
  const float4 vij = ((const float4*)(r_ij + base))[lane];
  const float4 vik = ((const float4*)(r_ik + base))[lane];
  const float4 vjk = ((const float4*)(r_jk + base))[lane];
  const int4   vm  = ((const int4*)(mask + base))[lane];
  const float* fij = (const float*)&vij;
  const float* fik = (const float*)&vik;
  const float* fjk = (const float*)&vjk;
  const int*   im  = (const int*)&vm;

  // accumulators G[e][z] flattened: v[e*4+z]
  float v[32];
#pragma unroll
  for (int i = 0; i < 32; ++i) v[i] = 0.0f;

#pragma unroll
  for (int u = 0; u < 4; ++u) {
    const float rij = fij[u], rik = fik[u], rjk = fjk[u];

    const float r2  = fmaf(rik, rik, rij * rij);
    const float num = fmaf(-rjk, rjk, r2);
    // cos_t = (r2 - rjk^2) / (2 rij rik); inputs guarantee rij,rik >= 0.5
    const float ct  = (0.5f * num) * __builtin_amdgcn_rcpf(rij * rik);
    const float x   = 1.0f - ct;
    // Behler cutoff 0.5*(cos(pi*r/6)+1): v_cos takes revolutions -> r/12.
    // r in [0.5,5.5] < RC=6 always, so no branch. The two 0.5 factors
    // (0.25 total) are folded into the epilogue coefficients.
    const float fci = __builtin_amdgcn_cosf(rij * (1.0f / 12.0f)) + 1.0f;
    const float fck = __builtin_amdgcn_cosf(rik * (1.0f / 12.0f)) + 1.0f;
    float fcp = fci * fck;
    fcp = (im[u] != 0) ? fcp : 0.0f;    // mask zeroes the whole contribution

    // x^zeta, zeta = {1,2,4,16}, by repeated squaring
    const float x2 = x * x, x4 = x2 * x2, x8 = x4 * x4, x16 = x8 * x8;
    const float b0 = x * fcp, b1 = x2 * fcp, b2 = x4 * fcp, b3 = x16 * fcp;

    const float r2n = r2 * NLOG2E;      // exp(-eta*r2) = exp2(r2n*eta)
#pragma unroll
    for (int e = 0; e < 8; ++e) {
      const float w = __builtin_amdgcn_exp2f(r2n * etas[e]);  // etas in SGPRs
      v[e * 4 + 0] = fmaf(w, b0, v[e * 4 + 0]);
      v[e * 4 + 1] = fmaf(w, b1, v[e * 4 + 1]);
      v[e * 4 + 2] = fmaf(w, b2, v[e * 4 + 2]);
      v[e * 4 + 3] = fmaf(w, b3, v[e * 4 + 3]);
    }
  }

  // reduce-scatter across the wave: 32 values over 64 lanes
  rs_round<1, 16>(v, lane);
  rs_round<2, 8>(v, lane);
  rs_round<4, 4>(v, lane);
  rs_round<8, 2>(v, lane);
  rs_round<16, 1>(v, lane);
  v[0] += __shfl_xor(v[0], 32, 64);     // merge the two 32-lane groups

  // combine the two half-row waves via LDS (2-way bank aliasing = free)
  __shared__ float lds[4][64];
  lds[wave][lane] = v[0];
  __syncthreads();
  const float sum = v[0] + lds[wave ^ 1][lane];

  const int vidx = __brev(lane & 31) >> 27;  // value id this lane holds
  const int e = vidx >> 2;
  const int z = vidx & 3;

  // zetas = {1,2,4,16}; coefs include the folded 0.25 cutoff factor:
  // lo = 0.25*2^(1-z) = 2^(-1-z), hi = 0.25*2^(1+z) = 2^(z-1)
  // wave half==0 stores the lo half (lanes<32), half==1 the hi half (lanes>=32)
  if ((lane >> 5) == half) {
    float coef;
    int aoff;
    if (half == 0) {
      coef = (z == 0) ? 0.25f : (z == 1) ? 0.125f : (z == 2) ? 0.03125f
                                                             : 7.62939453125e-06f;
      aoff = z;
    } else {
      coef = (z == 0) ? 1.0f : (z == 1) ? 2.0f : (z == 2) ? 8.0f : 32768.0f;
      aoff = 4 + z;
    }
    out[(size_t)row * 64 + e * 8 + aoff] = sum * coef;
  }
}

extern "C" void kernel_launch(void* const* d_in, const int* in_sizes, int n_in,
                              void* d_out, int out_size, void* d_ws, size_t ws_size,
                              hipStream_t stream) {
  const float* r_ij = (const float*)d_in[0];
  const float* r_ik = (const float*)d_in[1];
  const float* r_jk = (const float*)d_in[2];
  const int*   mask = (const int*)d_in[3];
  const float* etas = (const float*)d_in[4];
  float* out = (float*)d_out;

  const int rows   = in_sizes[0] / 512;   // B*N = 4096
  const int blocks = rows / 2;            // 2 rows (4 waves) per block

  behler_g3_kernel<<<blocks, 256, 0, stream>>>(r_ij, r_ik, r_jk, mask, etas, out);
}